// Round 2
// baseline (3416.271 us; speedup 1.0000x reference)
//
#include <hip/hip_runtime.h>
#include <hip/hip_fp16.h>

// Bidirectional GRU (B=64,S=1024,E=H=256) + FC/ReLU head — chunked pipeline.
// ws need = CT*196608 + 131072 bytes (CT=256 -> 50.5MB), chosen from ws_size at
// launch. gx stored f16 in CONSUMER order [dir][sc][bslice][tid512][24] so k_rec
// loads 48B/thread/step as 3x dwordx4. GRU h written f16 [t][b][512] straight
// into d_out (same bytes as the f32 [t][b][256] output); k_fc converts in place.
// All static LDS <= 64KB.

typedef _Float16 f16x8 __attribute__((ext_vector_type(8)));
typedef float    f32x4 __attribute__((ext_vector_type(4)));

#define MFMA(a,b,c) __builtin_amdgcn_mfma_f32_16x16x32_f16((a),(b),(c),0,0,0)
// swizzled byte addr for [rows][256 f16] (512B rows) and [rows][512 f16] (1024B rows):
// XOR row-bits into the 16B-slot bits to break the bank-aligned row stride.
#define SWZ(r,c)  ((((r)*512)  + (c)) ^ (((r)&7)<<4))
#define SWZ2(r,c) ((((r)*1024) + (c)) ^ (((r)&7)<<4))

__device__ inline f16x8 pack8(float4 a, float4 b){
  f16x8 h;
  h[0]=(_Float16)a.x; h[1]=(_Float16)a.y; h[2]=(_Float16)a.z; h[3]=(_Float16)a.w;
  h[4]=(_Float16)b.x; h[5]=(_Float16)b.y; h[6]=(_Float16)b.z; h[7]=(_Float16)b.w;
  return h;
}
__device__ inline float fsigm(float x){
  return __builtin_amdgcn_rcpf(1.f + __expf(-x));
}
__device__ inline float ftanh(float x){
  float e = __expf(2.f*x);                   // +inf -> 1, 0 -> -1
  return 1.f - 2.f*__builtin_amdgcn_rcpf(e + 1.f);
}

// ---------------- gx chunk: gx = x @ W_ih^T + b_ih (+ b_hh for r,z gates) ----------------
// grid (CT, 2 dir), 256 threads. Block handles sequence position p = sbase+tc
// (t = dir ? 1023-p : p); stages X[:,t,:] once, loops 12 col-tiles of 64.
// Output written f16 scattered into consumer order.
__global__ __launch_bounds__(256) void k_gx(
    const float* __restrict__ X,
    const float* __restrict__ Wf, const float* __restrict__ bihf, const float* __restrict__ bhhf,
    const float* __restrict__ Wb, const float* __restrict__ bihb, const float* __restrict__ bhhb,
    _Float16* __restrict__ gxc, int CT, int sbase)
{
  const int tc = blockIdx.x, dir = blockIdx.y;
  const int p = sbase + tc;
  const int t = dir ? (1023 - p) : p;
  const float* __restrict__ Wp = dir ? Wb : Wf;
  const float* __restrict__ bi = dir ? bihb : bihf;
  const float* __restrict__ bh = dir ? bhhb : bhhf;
  __shared__ _Float16 As[64*256];            // 32KB
  __shared__ _Float16 Bs[64*256];            // 32KB  (total 64KB exactly)
  const int tid = threadIdx.x;
  #pragma unroll
  for (int i = 0; i < 8; ++i) {              // stage A: rows = batch b, fixed t
    int c = tid + i*256, r = c >> 5, cc = c & 31;
    const float4* s4 = (const float4*)(X + ((size_t)r*1024 + t)*256 + cc*8);
    *(f16x8*)((char*)As + SWZ(r, cc*16)) = pack8(s4[0], s4[1]);
  }
  const int w = tid >> 6, l = tid & 63, lr = l & 15, g = l >> 4;
  const size_t obase = (((size_t)dir*CT + tc)*4 + w) * (size_t)(512*24);
  #pragma unroll 1
  for (int nt = 0; nt < 12; ++nt) {
    __syncthreads();                         // prev iter's Bs readers done
    #pragma unroll
    for (int i = 0; i < 8; ++i) {            // stage B: W rows nt*64..+64
      int c = tid + i*256, r = c >> 5, cc = c & 31;
      const float4* s4 = (const float4*)(Wp + (size_t)(nt*64 + r)*256 + cc*8);
      *(f16x8*)((char*)Bs + SWZ(r, cc*16)) = pack8(s4[0], s4[1]);
    }
    __syncthreads();
    f32x4 acc[4];
    #pragma unroll
    for (int ct = 0; ct < 4; ++ct) acc[ct] = (f32x4){0.f,0.f,0.f,0.f};
    #pragma unroll
    for (int kk = 0; kk < 8; ++kk) {
      f16x8 af = *(const f16x8*)((const char*)As + SWZ(w*16 + lr, kk*64 + g*16));
      #pragma unroll
      for (int ct = 0; ct < 4; ++ct) {
        f16x8 bfr = *(const f16x8*)((const char*)Bs + SWZ(ct*16 + lr, kk*64 + g*16));
        acc[ct] = MFMA(af, bfr, acc[ct]);
      }
    }
    #pragma unroll
    for (int ct = 0; ct < 4; ++ct) {         // D: col = lane&15, row = g*4+q (+w*16)
      const int col = nt*64 + ct*16 + lr;
      const float bv = bi[col] + (col < 512 ? bh[col] : 0.f);  // fold bhh for r,z
      const int jj = col & 255;
      const int tid2 = (jj>>5)*64 + g*16 + lr;          // consumer thread
      const int idx0 = ((col>>8)*2 + ((jj>>4)&1))*4;    // consumer ct*4
      #pragma unroll
      for (int q = 0; q < 4; ++q)
        gxc[obase + (size_t)tid2*24 + idx0 + q] = (_Float16)(acc[ct][q] + bv);
    }
  }
}

// ---------------- GRU recurrence, one chunk of CT steps ----------------
// grid 8 = (2 dirs x 4 batch-slices of 16), 512 threads (8 waves). Wave w owns
// cols j in [w*32,w*32+32) of all 3 gates; W_hh f16 B-frags resident in VGPRs
// (6 tiles x 8 k-steps x 4 dwords = 192 VGPR). h broadcast via swizzled LDS.
// h-state persists across chunk launches in wsh (f32 [2][64][256]).
__global__ __launch_bounds__(512) void k_rec(
    const float* __restrict__ Whh_f, const float* __restrict__ bhh_f,
    const float* __restrict__ Whh_b, const float* __restrict__ bhh_b,
    const _Float16* __restrict__ gxc, float* __restrict__ wsh,
    _Float16* __restrict__ out16, float* __restrict__ hidden,
    int CT, int sbase)
{
  const int dir = blockIdx.x & 1;
  const int bsl = blockIdx.x >> 1;
  const int bbase = bsl * 16;
  const float* __restrict__ Whh = dir ? Whh_b : Whh_f;
  const float* __restrict__ bhh = dir ? bhh_b : bhh_f;
  const int tid = threadIdx.x, w = tid >> 6, l = tid & 63;
  const int lr = l & 15, g = l >> 4;
  const int j0 = w * 32;
  f16x8 wf[6][8];                            // B-frag: W[col=colg][k=kk*32+g*8+i]
  #pragma unroll
  for (int ct = 0; ct < 6; ++ct) {
    const int colg = (ct>>1)*256 + j0 + (ct&1)*16 + lr;
    #pragma unroll
    for (int kk = 0; kk < 8; ++kk) {
      const float4* s4 = (const float4*)(Whh + (size_t)colg*256 + kk*32 + g*8);
      wf[ct][kk] = pack8(s4[0], s4[1]);
    }
  }
  const float bn0 = bhh[512 + j0 + lr];      // n-gate bhh (inside r*(.), can't fold)
  const float bn1 = bhh[512 + j0 + 16 + lr];
  __shared__ _Float16 hs[16*256];            // 8KB h tile, swizzled
  float hold[2][4];
  if (sbase == 0) {
    *(int4*)((char*)hs + tid*16) = make_int4(0,0,0,0);
    #pragma unroll
    for (int jt = 0; jt < 2; ++jt)
      #pragma unroll
      for (int q = 0; q < 4; ++q) hold[jt][q] = 0.f;
  } else {                                   // restore h from previous chunk
    const int r = tid >> 5, cc = tid & 31;
    const float4* s4 = (const float4*)(wsh + ((size_t)(dir*64 + bbase + r))*256 + cc*8);
    *(f16x8*)((char*)hs + SWZ(r, cc*16)) = pack8(s4[0], s4[1]);
    #pragma unroll
    for (int jt = 0; jt < 2; ++jt)
      #pragma unroll
      for (int q = 0; q < 4; ++q)
        hold[jt][q] = wsh[((size_t)(dir*64 + bbase + g*4 + q))*256 + j0 + jt*16 + lr];
  }
  __syncthreads();
  #pragma unroll 1
  for (int sc = 0; sc < CT; ++sc) {
    // gx for this step, consumer-ordered: 3 x dwordx4. Issued here, consumed
    // after the post-MFMA barrier (vmcnt drain hides L2/L3 latency under MFMA).
    const _Float16* gp = gxc + ((((size_t)dir*CT + sc)*4 + bsl)*512 + (size_t)tid)*24;
    const f16x8 gv0 = *(const f16x8*)(gp);
    const f16x8 gv1 = *(const f16x8*)(gp + 8);
    const f16x8 gv2 = *(const f16x8*)(gp + 16);
    f32x4 acc[6];
    #pragma unroll
    for (int ct = 0; ct < 4; ++ct) acc[ct] = (f32x4){0.f,0.f,0.f,0.f};
    acc[4] = (f32x4){bn0,bn0,bn0,bn0};
    acc[5] = (f32x4){bn1,bn1,bn1,bn1};
    #pragma unroll
    for (int kk = 0; kk < 8; ++kk) {
      f16x8 af = *(const f16x8*)((const char*)hs + SWZ(lr, kk*64 + g*16));
      #pragma unroll
      for (int ct = 0; ct < 6; ++ct) acc[ct] = MFMA(af, wf[ct][kk], acc[ct]);
    }
    __syncthreads();                         // all waves done reading hs
    const int s = sbase + sc;
    const int t = dir ? (1023 - s) : s;
    #pragma unroll
    for (int jt = 0; jt < 2; ++jt) {
      #pragma unroll
      for (int q = 0; q < 4; ++q) {
        const float xr = (float)gv0[jt*4 + q];       // idx = ct*4+q, ct=jt
        const float xz = (float)gv1[jt*4 + q];       // ct=2+jt
        const float xn = (float)gv2[jt*4 + q];       // ct=4+jt
        const float r = fsigm(xr + acc[jt][q]);
        const float z = fsigm(xz + acc[2+jt][q]);
        const float n = ftanh(xn + r*acc[4+jt][q]);
        const float h = n + z*(hold[jt][q] - n);     // (1-z)n + z h
        hold[jt][q] = h;
        const int row = g*4 + q;                     // local batch row
        const int j = j0 + jt*16 + lr;
        *(_Float16*)((char*)hs + SWZ(row, j*2)) = (_Float16)h;
        out16[((size_t)t*64 + bbase + row)*512 + dir*256 + j] = (_Float16)h;
        if (s == 1023) hidden[((size_t)(dir*64 + bbase + row))*256 + j] = h;
      }
    }
    __syncthreads();                         // hs writes visible before next read
  }
  if (sbase + CT < 1024) {                   // persist h for next chunk
    #pragma unroll
    for (int jt = 0; jt < 2; ++jt)
      #pragma unroll
      for (int q = 0; q < 4; ++q)
        wsh[((size_t)(dir*64 + bbase + g*4 + q))*256 + j0 + jt*16 + lr] = hold[jt][q];
  }
}

// ---------------- FC in place: relu(concat_f16 @ W_fc^T + b) -> f32 ----------------
// grid 1024 (one block per t), 256 threads. Stage the full 64x512 f16 row block
// into LDS FIRST (barrier drains the reads), then overwrite the same bytes with
// f32 results. W_fc B-fragments streamed global->reg (L2-hot, 512KB).
__global__ __launch_bounds__(256) void k_fc(
    const _Float16* __restrict__ h16, const float* __restrict__ Wfc,
    const float* __restrict__ bfc, float* __restrict__ out)
{
  const int mt = blockIdx.x;
  __shared__ _Float16 As[64*512];            // 64KB exactly
  const int tid = threadIdx.x, w = tid >> 6, l = tid & 63;
  const int lr = l & 15, g = l >> 4;
  #pragma unroll
  for (int i = 0; i < 16; ++i) {
    int c = tid + i*256, r = c >> 6, cc = c & 63;
    *(int4*)((char*)As + SWZ2(r, cc*16)) =
        *(const int4*)((const char*)h16 + ((size_t)mt*64 + r)*1024 + cc*16);
  }
  __syncthreads();                           // all h16 reads drained before any store
  #pragma unroll 1
  for (int nt = 0; nt < 4; ++nt) {
    f32x4 acc[4];
    #pragma unroll
    for (int ct = 0; ct < 4; ++ct) acc[ct] = (f32x4){0.f,0.f,0.f,0.f};
    #pragma unroll 2
    for (int kk = 0; kk < 16; ++kk) {
      f16x8 af = *(const f16x8*)((const char*)As + SWZ2(w*16 + lr, kk*64 + g*16));
      #pragma unroll
      for (int ct = 0; ct < 4; ++ct) {
        const float4* s4 = (const float4*)(Wfc + (size_t)(nt*64 + ct*16 + lr)*512 + kk*32 + g*8);
        acc[ct] = MFMA(af, pack8(s4[0], s4[1]), acc[ct]);
      }
    }
    #pragma unroll
    for (int ct = 0; ct < 4; ++ct) {
      const int col = nt*64 + ct*16 + lr;
      const float bv = bfc[col];
      #pragma unroll
      for (int q = 0; q < 4; ++q) {
        const int row = w*16 + g*4 + q;
        out[((size_t)mt*64 + row)*256 + col] = fmaxf(acc[ct][q] + bv, 0.f);
      }
    }
  }
}

extern "C" void kernel_launch(void* const* d_in, const int* in_sizes, int n_in,
                              void* d_out, int out_size, void* d_ws, size_t ws_size,
                              hipStream_t stream) {
  const float* X      = (const float*)d_in[0];
  const float* W_ih_f = (const float*)d_in[1];
  const float* W_hh_f = (const float*)d_in[2];
  const float* b_ih_f = (const float*)d_in[3];
  const float* b_hh_f = (const float*)d_in[4];
  const float* W_ih_b = (const float*)d_in[5];
  const float* W_hh_b = (const float*)d_in[6];
  const float* b_ih_b = (const float*)d_in[7];
  const float* b_hh_b = (const float*)d_in[8];
  const float* W_fc   = (const float*)d_in[9];
  const float* b_fc   = (const float*)d_in[10];

  // Pick chunk length from ws_size: need CT*196608 + 131072 bytes.
  int CT = 256;
  while (CT > 8 && ((size_t)CT*196608 + 131072) > ws_size) CT >>= 1;
  _Float16* gxc = (_Float16*)d_ws;                     // [2][CT][4][512][24] f16
  float*    wsh = (float*)((char*)d_ws + (size_t)CT*196608);  // [2][64][256] f32

  _Float16* h16   = (_Float16*)d_out;                  // [1024][64][512] f16 (in-place)
  float*    out   = (float*)d_out;                     // [1024][64][256] f32
  float*    hidden= (float*)d_out + (size_t)1024*64*256;

  const int NC = 1024 / CT;
  for (int c = 0; c < NC; ++c) {
    k_gx<<<dim3(CT, 2), dim3(256), 0, stream>>>(X, W_ih_f, b_ih_f, b_hh_f,
                                                W_ih_b, b_ih_b, b_hh_b, gxc, CT, c*CT);
    k_rec<<<dim3(8), dim3(512), 0, stream>>>(W_hh_f, b_hh_f, W_hh_b, b_hh_b,
                                             gxc, wsh, h16, hidden, CT, c*CT);
  }
  k_fc<<<dim3(1024), dim3(256), 0, stream>>>(h16, W_fc, b_fc, out);
}